// Round 1
// baseline (345.234 us; speedup 1.0000x reference)
//
#include <hip/hip_runtime.h>
#include <math.h>

// MultiHash: Instant-NGP style 2D multires hash encoding (L=16, T=2^14, F=2)
// + MLP 32 -> 64 -> 64 -> 3, fp32 throughout (threshold 8.9e-8 abs forbids bf16).
//
// Structure notes:
//  - layer1 fused into level loop: h1[j] accumulated as each level's 2 features
//    are produced (j unrolled -> h1 stays in registers; l rolled -> small code).
//  - layer3 fused into layer2 j-loop: h2[j] consumed immediately -> never stored.
//  - weights read via wave-uniform addresses on __restrict const ptrs -> SMEM loads.

#define TBL_MASK 16383u
#define PRIME1   2654435761u

struct ResArr { float r[16]; };

__global__ __launch_bounds__(256) void mh_fused(
    const float* __restrict__ x,
    const float* __restrict__ tables,
    const float* __restrict__ W1,
    const float* __restrict__ b1,
    const float* __restrict__ W2,
    const float* __restrict__ b2,
    const float* __restrict__ W3,
    const float* __restrict__ b3,
    float* __restrict__ out,
    ResArr res, int n)
{
    const int i = blockIdx.x * blockDim.x + threadIdx.x;
    if (i >= n) return;

    const float2 xv = reinterpret_cast<const float2*>(x)[i];

    // h1 accumulators (layer 1), init with bias (uniform scalar loads)
    float h1[64];
    #pragma unroll
    for (int j = 0; j < 64; ++j) h1[j] = b1[j];

    const float2* __restrict__ tbl2 = reinterpret_cast<const float2*>(tables);

    #pragma unroll 2
    for (int l = 0; l < 16; ++l) {
        const float r  = res.r[l];
        const float sx = xv.x * r;
        const float sy = xv.y * r;
        const float gx = floorf(sx);
        const float gy = floorf(sy);
        const unsigned ux = (unsigned)(int)gx;
        const unsigned uy = (unsigned)(int)gy;
        const unsigned hy0 = uy * PRIME1;
        const unsigned hy1 = hy0 + PRIME1;   // (uy+1)*PRIME1 mod 2^32
        const unsigned i00 = ( ux        ^ hy0) & TBL_MASK;
        const unsigned i10 = ((ux + 1u)  ^ hy0) & TBL_MASK;
        const unsigned i01 = ( ux        ^ hy1) & TBL_MASK;
        const unsigned i11 = ((ux + 1u)  ^ hy1) & TBL_MASK;
        const float2* tl = tbl2 + (l << 14);
        const float2 t00 = tl[i00];
        const float2 t10 = tl[i10];
        const float2 t01 = tl[i01];
        const float2 t11 = tl[i11];
        // weights exactly as reference: prod over dims of (1 - |scaled - corner|)
        const float wx0 = 1.0f - fabsf(sx - gx);
        const float wx1 = 1.0f - fabsf(sx - (gx + 1.0f));
        const float wy0 = 1.0f - fabsf(sy - gy);
        const float wy1 = 1.0f - fabsf(sy - (gy + 1.0f));
        const float w00 = wx0 * wy0;
        const float w10 = wx1 * wy0;
        const float w01 = wx0 * wy1;
        const float w11 = wx1 * wy1;
        const float f0 = fmaf(w00, t00.x, fmaf(w10, t10.x, fmaf(w01, t01.x, w11 * t11.x)));
        const float f1 = fmaf(w00, t00.y, fmaf(w10, t10.y, fmaf(w01, t01.y, w11 * t11.y)));
        // fused layer-1 accumulate: h1[j] += W1[j][2l]*f0 + W1[j][2l+1]*f1
        const float* __restrict__ w1c = W1 + 2 * l;
        #pragma unroll
        for (int j = 0; j < 64; ++j) {
            float a = h1[j];
            a = fmaf(w1c[j * 32],     f0, a);
            a = fmaf(w1c[j * 32 + 1], f1, a);
            h1[j] = a;
        }
    }

    #pragma unroll
    for (int j = 0; j < 64; ++j) h1[j] = fmaxf(h1[j], 0.0f);

    // layer 2 (rolled over j, inner k unrolled) fused with layer 3
    float o0 = b3[0], o1 = b3[1], o2 = b3[2];
    #pragma unroll 2
    for (int j = 0; j < 64; ++j) {
        float acc = b2[j];
        const float* __restrict__ w2r = W2 + j * 64;
        #pragma unroll
        for (int k = 0; k < 64; ++k) acc = fmaf(w2r[k], h1[k], acc);
        const float h2j = fmaxf(acc, 0.0f);
        o0 = fmaf(W3[j],       h2j, o0);
        o1 = fmaf(W3[64 + j],  h2j, o1);
        o2 = fmaf(W3[128 + j], h2j, o2);
    }

    float* op = out + 3 * (long)i;
    op[0] = o0; op[1] = o1; op[2] = o2;
}

extern "C" void kernel_launch(void* const* d_in, const int* in_sizes, int n_in,
                              void* d_out, int out_size, void* d_ws, size_t ws_size,
                              hipStream_t stream) {
    const float* x      = (const float*)d_in[0];
    const float* tables = (const float*)d_in[1];
    const float* W1     = (const float*)d_in[2];
    const float* b1v    = (const float*)d_in[3];
    const float* W2     = (const float*)d_in[4];
    const float* b2v    = (const float*)d_in[5];
    const float* W3     = (const float*)d_in[6];
    const float* b3v    = (const float*)d_in[7];
    float* out = (float*)d_out;

    const int n = in_sizes[0] / 2;   // B

    // Replicate numpy's RES computation on the host (glibc libm, float64),
    // matching np.floor(16 * b**k) bit-for-bit as closely as possible.
    // RES boundary levels (k=3,6,9,12,15) sit at exact integers -> floor is
    // last-ulp sensitive; if validation fails at ~1e-6 absmax, flip those.
    ResArr ra;
    const double bb = exp((log(512.0) - log(16.0)) / 15.0);
    for (int k = 0; k < 16; ++k) ra.r[k] = (float)floor(16.0 * pow(bb, (double)k));

    dim3 grid((n + 255) / 256), block(256);
    hipLaunchKernelGGL(mh_fused, grid, block, 0, stream,
                       x, tables, W1, b1v, W2, b2v, W3, b3v, out, ra, n);
}